// Round 2
// baseline (58182.092 us; speedup 1.0000x reference)
//
#include <hip/hip_runtime.h>
#include <math.h>

// h_t = tanh(A h_{t-1} + B x_t + c), A = 0.9 I + 0.1 A_raw
// T=16384, X=512, H=1024, fp32. Output: all h_t, [T, H].
//
// Phase 1: Bx = x @ B^T + c written in-place into d_out (row t consumed
//          exactly once at step t, then overwritten with h_t).
// Phase 2: XCD-local tagged-ring pipeline, HANG-PROOF version:
//   - 512 candidate blocks; per-XCD claim counters (device atomics); first
//     XCD to 64 claimants is CAS-elected; its 64 blocks (co-resident on one
//     XCD: 2 blocks/CU x 32 CUs) run the scan, everyone else exits.
//     Termination: launch_bounds(512,4) caps VGPR<=128 + 8.2KB LDS ->
//     2 blocks/CU -> all 512 resident -> all claim -> pigeonhole forces
//     some counter to 64.
//   - TAGS (validated baseline scheme) make stale data self-identifying
//     under ANY cache behavior: slot for h_t holds (value, tag=t+1); stale
//     tags are t-3k, never t. No grid barrier, no poison values.
//   - Producer packet stores: sc0 sc1 (validated write-through to LLC) ->
//     data always globally visible; liveness never depends on L2 scope.
//   - Consumer poll: first 6 spins `sc0` (candidate same-XCD L2 fast path,
//     ~200cy vs ~600cy LLC RT), then escalate to `sc0 sc1` (validated).
//     Correct + live in every semantics world; fast iff sc0 hits L2.
//   - Ring depth 3 (sufficient: producer at t overwrites h_{t-3}; reaching
//     step t implies every block passed its step t-1 poll, hence finished
//     reading h_{t-3} at step t-2). slots+ctrl = 24612B < 32KB ws bound.
//   - Detected values go to LDS (double-buffered), __syncthreads, each wave
//     reads h once from LDS and computes BOTH its rows.

#define T_STEPS 16384
#define XD 512
#define HD 1024

typedef unsigned int uint32x4 __attribute__((ext_vector_type(4)));

// ---------------------------------------------------------------------------
// Phase 1: GEMM  out[t][i] = sum_k x[t][k] * B[i][k] + c[i]   (unchanged)
// ---------------------------------------------------------------------------
__global__ __launch_bounds__(256) void gemm_bx_kernel(
    const float* __restrict__ x, const float* __restrict__ B,
    const float* __restrict__ c, float* __restrict__ out)
{
    __shared__ __align__(16) float xs[32][68];  // [k][t]
    __shared__ __align__(16) float bs[32][68];  // [k][i]

    const int tid = threadIdx.x;
    const int t0 = blockIdx.x * 64;
    const int i0 = blockIdx.y * 64;
    const int tx = tid & 15;
    const int ty = tid >> 4;
    const int lr = tid >> 3;
    const int lc = (tid & 7) << 2;

    float acc[4][4] = {{0.f}};

    for (int k0 = 0; k0 < XD; k0 += 32) {
        const float4 xa = *(const float4*)&x[(size_t)(t0 + lr) * XD + k0 + lc];
        const float4 xb = *(const float4*)&x[(size_t)(t0 + lr + 32) * XD + k0 + lc];
        const float4 ba = *(const float4*)&B[(size_t)(i0 + lr) * XD + k0 + lc];
        const float4 bb = *(const float4*)&B[(size_t)(i0 + lr + 32) * XD + k0 + lc];
        __syncthreads();
        xs[lc + 0][lr] = xa.x; xs[lc + 1][lr] = xa.y; xs[lc + 2][lr] = xa.z; xs[lc + 3][lr] = xa.w;
        xs[lc + 0][lr + 32] = xb.x; xs[lc + 1][lr + 32] = xb.y; xs[lc + 2][lr + 32] = xb.z; xs[lc + 3][lr + 32] = xb.w;
        bs[lc + 0][lr] = ba.x; bs[lc + 1][lr] = ba.y; bs[lc + 2][lr] = ba.z; bs[lc + 3][lr] = ba.w;
        bs[lc + 0][lr + 32] = bb.x; bs[lc + 1][lr + 32] = bb.y; bs[lc + 2][lr + 32] = bb.z; bs[lc + 3][lr + 32] = bb.w;
        __syncthreads();
        #pragma unroll
        for (int k = 0; k < 32; ++k) {
            const float4 av = *(const float4*)&xs[k][ty << 2];
            const float4 bv = *(const float4*)&bs[k][tx << 2];
            const float am[4] = {av.x, av.y, av.z, av.w};
            const float bn[4] = {bv.x, bv.y, bv.z, bv.w};
            #pragma unroll
            for (int m = 0; m < 4; ++m)
                #pragma unroll
                for (int n = 0; n < 4; ++n)
                    acc[m][n] = fmaf(am[m], bn[n], acc[m][n]);
        }
    }

    #pragma unroll
    for (int m = 0; m < 4; ++m) {
        const int trow = t0 + (ty << 2) + m;
        #pragma unroll
        for (int n = 0; n < 4; ++n) {
            const int icol = i0 + (tx << 2) + n;
            out[(size_t)trow * HD + icol] = acc[m][n] + c[icol];
        }
    }
}

// ---------------------------------------------------------------------------
// Ring + control init (d_ws is poisoned 0xAA before every launch).
// slots: ull[3][1024]; ring[2] = h0 tag 0; rings 0,1 = impossible tag.
// ctrl:  [0..7] per-XCD claim counters = 0, [8] winner = 0xFFFFFFFF.
// Total footprint: 3*8KB + 36B = 24612B.
// ---------------------------------------------------------------------------
__global__ void init_slots_kernel(unsigned long long* slots, unsigned* ctrl,
                                  const float* h0)
{
    const int i = threadIdx.x;  // 1024 threads
    union { float f; unsigned u; } v; v.f = h0[i];
    slots[2 * HD + i] = (unsigned long long)v.u;          // tag 0 | h0 bits
    slots[0 * HD + i] = 0xFFFFFFFF00000000ull;
    slots[1 * HD + i] = 0xFFFFFFFF00000000ull;
    if (i < 9) ctrl[i] = (i == 8) ? 0xFFFFFFFFu : 0u;
}

// ---------------------------------------------------------------------------
// Phase 2: XCD-local scan. 512 candidate blocks; 64 winners (one XCD);
// winner block b's wave w owns rows 16b + 2w and 16b + 2w + 1.
// ---------------------------------------------------------------------------
__global__ __launch_bounds__(512, 4) void rnn_scan_kernel(
    const float* __restrict__ A_raw, float* out,
    unsigned long long* slots, unsigned* ctrl)
{
    // ---- XCD election -----------------------------------------------------
    __shared__ int s_bid;
    if (threadIdx.x == 0) {
        unsigned xcd;
        asm volatile("s_getreg_b32 %0, hwreg(HW_REG_XCC_ID)" : "=s"(xcd));
        xcd &= 7u;
        int my = -1;
        const unsigned slot = atomicAdd(&ctrl[xcd], 1u);
        if (slot < 64u) {
            if (slot == 63u) atomicCAS(&ctrl[8], 0xFFFFFFFFu, xcd);
            // Wait for a winner (guaranteed: 512 resident claims / 8 XCDs).
            unsigned w;
            const unsigned* wp = &ctrl[8];
            do {
                asm volatile(
                    "global_load_dword %0, %1, off sc0 sc1\n\t"
                    "s_waitcnt vmcnt(0)"
                    : "=v"(w) : "v"(wp));
            } while (w == 0xFFFFFFFFu);
            if (w == xcd) my = (int)slot;
        }
        s_bid = my;
    }
    __syncthreads();
    const int bid = s_bid;       // 0..63 on the winning XCD, else -1
    if (bid < 0) return;

    // ---- scan -------------------------------------------------------------
    const int tid = threadIdx.x;       // 0..511
    const int wave = tid >> 6;         // 0..7
    const int lane = tid & 63;
    const int r0 = (bid << 4) + (wave << 1);   // rows r0, r0+1

    __shared__ float hlds[2][HD];

    // Effective A rows: A_eff[r][k] = 0.1*A_raw[r][k] + 0.9*(k==r)
    float aw0[16], aw1[16];
    #pragma unroll
    for (int j = 0; j < 16; ++j) {
        const int k = lane + (j << 6);
        float v0 = 0.1f * A_raw[(size_t)r0 * HD + k];
        float v1 = 0.1f * A_raw[(size_t)(r0 + 1) * HD + k];
        if (k == r0) v0 += 0.9f;
        if (k == r0 + 1) v1 += 0.9f;
        aw0[j] = v0; aw1[j] = v1;
    }

    // Prefetch Bx for t=0.
    float2 bxn = *(const float2*)&out[r0];

    int cs = 2;   // ring slot of h_{t-1}  ((t+2) % 3; h0 lives in slot 2)
    int ps = 0;   // ring slot of h_t      (t % 3)

    for (int t = 0; t < T_STEPS; ++t) {
        const float2 bx = bxn;

        // Poll my two adjacent slots of h_{t-1}; expect tag t.
        // Spins 0..5: sc0 (candidate same-XCD L2 fast path).
        // Spins >=6:  sc0 sc1 (validated LLC-coherent path) -> guaranteed
        // progress because the producer stored write-through (sc0 sc1).
        // Tag match at step t can only come from the step-t store (stale
        // tags are t-3k), so ANY serving cache is correctness-safe.
        const unsigned long long* sp =
            slots + ((size_t)cs << 10) + (tid << 1);
        uint32x4 s;
        int spin = 0;
        for (;;) {
            if (__builtin_expect(spin < 6, 1)) {
                asm volatile(
                    "global_load_dwordx4 %0, %1, off sc0\n\t"
                    "s_waitcnt vmcnt(0)"
                    : "=v"(s) : "v"(sp));
            } else {
                asm volatile(
                    "global_load_dwordx4 %0, %1, off sc0 sc1\n\t"
                    "s_waitcnt vmcnt(0)"
                    : "=v"(s) : "v"(sp));
            }
            if (s.y == (unsigned)t && s.w == (unsigned)t) break;
            ++spin;
        }

        union { unsigned u; float f; } c0, c1; c0.u = s.x; c1.u = s.z;
        *(float2*)&hlds[t & 1][tid << 1] = make_float2(c0.f, c1.f);
        __syncthreads();

        // Prefetch next step's Bx while h is consumed.
        const int tn = (t + 1 < T_STEPS) ? (t + 1) : t;
        bxn = *(const float2*)&out[(size_t)tn * HD + r0];

        // Both rows' dot products from ONE pass over h in LDS.
        const float* hl = hlds[t & 1];
        float p0 = 0.f, p1 = 0.f;
        #pragma unroll
        for (int j = 0; j < 16; ++j) {
            const float hvj = hl[lane + (j << 6)];
            p0 = fmaf(aw0[j], hvj, p0);
            p1 = fmaf(aw1[j], hvj, p1);
        }

        // wave-wide sums (64 lanes)
        #pragma unroll
        for (int off = 32; off >= 1; off >>= 1) {
            p0 += __shfl_xor(p0, off, 64);
            p1 += __shfl_xor(p1, off, 64);
        }

        if (lane == 0) {
            const float h0n = tanhf(p0 + bx.x);
            const float h1n = tanhf(p1 + bx.y);
            *(float2*)&out[(size_t)t * HD + r0] = make_float2(h0n, h1n);
            union { float f; unsigned u; } u0, u1; u0.f = h0n; u1.f = h1n;
            uint32x4 pkt;
            pkt.x = u0.u; pkt.y = (unsigned)(t + 1);
            pkt.z = u1.u; pkt.w = (unsigned)(t + 1);
            unsigned long long* dp = slots + ((size_t)ps << 10) + r0;
            asm volatile(
                "global_store_dwordx4 %0, %1, off sc0 sc1"
                :: "v"(dp), "v"(pkt) : "memory");
        }
        // Advance ring indices: cons_{t+1} = prod_t; prod_{t+1} = prod_t+1.
        cs = ps;
        ps = (ps + 1 == 3) ? 0 : ps + 1;
        // No grid barrier: tags + 3-deep ring + dataflow (skew <= 1) suffice.
        // LDS double buffer covers intra-block wave skew.
    }
}

// ---------------------------------------------------------------------------
extern "C" void kernel_launch(void* const* d_in, const int* in_sizes, int n_in,
                              void* d_out, int out_size, void* d_ws, size_t ws_size,
                              hipStream_t stream)
{
    const float* x     = (const float*)d_in[0];  // [16384, 512]
    const float* h0    = (const float*)d_in[1];  // [1024]
    const float* A_raw = (const float*)d_in[2];  // [1024, 1024]
    const float* B     = (const float*)d_in[3];  // [1024, 512]
    const float* c     = (const float*)d_in[4];  // [1024]
    float* out = (float*)d_out;                  // [16384, 1024]
    unsigned long long* slots = (unsigned long long*)d_ws;  // 3 x 1024 x 8B
    unsigned* ctrl = (unsigned*)(slots + 3 * HD);           // 9 x 4B

    dim3 gemm_grid(T_STEPS / 64, HD / 64);       // 256 x 16
    gemm_bx_kernel<<<gemm_grid, 256, 0, stream>>>(x, B, c, out);
    init_slots_kernel<<<1, HD, 0, stream>>>(slots, ctrl, h0);
    rnn_scan_kernel<<<512, 512, 0, stream>>>(A_raw, out, slots, ctrl);
}

// Round 6
// 20728.000 us; speedup vs baseline: 2.8069x; 2.8069x over previous
//
#include <hip/hip_runtime.h>
#include <math.h>

// h_t = tanh(A h_{t-1} + B x_t + c), A = 0.9 I + 0.1 A_raw
// T=16384, X=512, H=1024, fp32. Output: all h_t, [T, H].
//
// Phase 1: Bx = x @ B^T + c written in-place into d_out (row t consumed
//          exactly once at step t, then overwritten with h_t).
// Phase 2: barrier-free tagged-slot pipeline -- the VALIDATED round-0
//   transport, restored verbatim:
//   - 64 blocks x 512 threads; wave w of block b owns rows 16b+2w, +1.
//   - h_t element j is an 8B (value, tag=t+1) packet in a 4-deep ring of
//     1024-slot buffers; h0 tag 0 in ring[3]. Stale data self-identifying.
//   - Poll: ONE global_load_dwordx4 sc0 sc1 with s_waitcnt vmcnt(0) INSIDE
//     the asm block -> every writeback is synchronous with the asm stmt;
//     no in-flight loads ever cross compiler-generated code.
//     (Rounds 3-5 post-mortem: counted vmcnt + in-flight asm loads is
//     UNSOUND at HIP level -- live-range splits move variables to new
//     physical regs, the straggler's async writeback clobbers whatever
//     now owns the old reg. Abandoned.)
//   - LDS double-buffer + __syncthreads per step (validated).
//
// Round-6 changes (compute-tail only; sync/transport untouched):
//   1. DPP wave reduction replaces the __shfl_xor butterfly. The butterfly
//      is 6 dependent LDS-crossbar ops (~250-300cy for p0+p1); the DPP
//      sequence (row_shr 1/2/4/8, row_bcast:15 rm=0xa, row_bcast:31
//      rm=0xc) is pure VALU (~100cy, two interleaved chains) and leaves
//      the full 64-lane sum in lane 63 -> lane 63 is now the producer.
//   2. fast_tanh = 1 - 2/(exp(2x)+1) via hardware __expf (~15 instr) vs
//      ocml tanhf (~40-60 instr). Exact at 0, saturates to +-1 correctly.
//   3. Packet store (inter-block critical path) issued before out store.
//   Numerics: new summation order + tanh rounding -> absmax moves off
//   0.00390625 by ~per-step 2e-7 x 16384 under norm<=1 Jacobian ≈ +3e-3
//   worst case; threshold is 2e-2.

#define T_STEPS 16384
#define XD 512
#define HD 1024

typedef unsigned int uint32x4 __attribute__((ext_vector_type(4)));

// DPP-accumulate: v += dpp_mov(v, ctrl) with masked/invalid lanes
// contributing 0.0f (old=0, bound_ctrl=true -> invalid reads return 0).
#define DPP_ADD(v, ctrl, rm)                                          \
    v += __int_as_float(__builtin_amdgcn_update_dpp(                  \
        0, __float_as_int(v), ctrl, rm, 0xf, true))

__device__ __forceinline__ float fast_tanh(float x)
{
    // tanh(x) = 1 - 2/(exp(2x)+1); exact at 0, saturates correctly:
    // x>>0: e=inf -> 1;  x<<0: e=0 -> -1.
    const float e = __expf(2.0f * x);
    return 1.0f - 2.0f / (e + 1.0f);
}

// ---------------------------------------------------------------------------
// Phase 1: GEMM  out[t][i] = sum_k x[t][k] * B[i][k] + c[i]   (unchanged)
// ---------------------------------------------------------------------------
__global__ __launch_bounds__(256) void gemm_bx_kernel(
    const float* __restrict__ x, const float* __restrict__ B,
    const float* __restrict__ c, float* __restrict__ out)
{
    __shared__ __align__(16) float xs[32][68];  // [k][t]
    __shared__ __align__(16) float bs[32][68];  // [k][i]

    const int tid = threadIdx.x;
    const int t0 = blockIdx.x * 64;
    const int i0 = blockIdx.y * 64;
    const int tx = tid & 15;        // i direction (4 outputs)
    const int ty = tid >> 4;        // t direction (4 outputs)
    const int lr = tid >> 3;        // staging row 0..31
    const int lc = (tid & 7) << 2;  // staging k 0,4,...,28

    float acc[4][4] = {{0.f}};

    for (int k0 = 0; k0 < XD; k0 += 32) {
        const float4 xa = *(const float4*)&x[(size_t)(t0 + lr) * XD + k0 + lc];
        const float4 xb = *(const float4*)&x[(size_t)(t0 + lr + 32) * XD + k0 + lc];
        const float4 ba = *(const float4*)&B[(size_t)(i0 + lr) * XD + k0 + lc];
        const float4 bb = *(const float4*)&B[(size_t)(i0 + lr + 32) * XD + k0 + lc];
        __syncthreads();
        xs[lc + 0][lr] = xa.x; xs[lc + 1][lr] = xa.y; xs[lc + 2][lr] = xa.z; xs[lc + 3][lr] = xa.w;
        xs[lc + 0][lr + 32] = xb.x; xs[lc + 1][lr + 32] = xb.y; xs[lc + 2][lr + 32] = xb.z; xs[lc + 3][lr + 32] = xb.w;
        bs[lc + 0][lr] = ba.x; bs[lc + 1][lr] = ba.y; bs[lc + 2][lr] = ba.z; bs[lc + 3][lr] = ba.w;
        bs[lc + 0][lr + 32] = bb.x; bs[lc + 1][lr + 32] = bb.y; bs[lc + 2][lr + 32] = bb.z; bs[lc + 3][lr + 32] = bb.w;
        __syncthreads();
        #pragma unroll
        for (int k = 0; k < 32; ++k) {
            const float4 av = *(const float4*)&xs[k][ty << 2];
            const float4 bv = *(const float4*)&bs[k][tx << 2];
            const float am[4] = {av.x, av.y, av.z, av.w};
            const float bn[4] = {bv.x, bv.y, bv.z, bv.w};
            #pragma unroll
            for (int m = 0; m < 4; ++m)
                #pragma unroll
                for (int n = 0; n < 4; ++n)
                    acc[m][n] = fmaf(am[m], bn[n], acc[m][n]);
        }
    }

    #pragma unroll
    for (int m = 0; m < 4; ++m) {
        const int trow = t0 + (ty << 2) + m;
        #pragma unroll
        for (int n = 0; n < 4; ++n) {
            const int icol = i0 + (tx << 2) + n;
            out[(size_t)trow * HD + icol] = acc[m][n] + c[icol];
        }
    }
}

// ---------------------------------------------------------------------------
// Slot-ring init (d_ws is poisoned 0xAA before every launch).
// ring[3] holds h0 with tag 0; rings 0..2 get an impossible tag.
// ---------------------------------------------------------------------------
__global__ void init_slots_kernel(unsigned long long* slots, const float* h0)
{
    const int i = threadIdx.x;  // 1024 threads
    union { float f; unsigned u; } v; v.f = h0[i];
    slots[3 * HD + i] = (unsigned long long)v.u;          // tag 0 | h0 bits
    slots[0 * HD + i] = 0xFFFFFFFF00000000ull;
    slots[1 * HD + i] = 0xFFFFFFFF00000000ull;
    slots[2 * HD + i] = 0xFFFFFFFF00000000ull;
}

// ---------------------------------------------------------------------------
// Phase 2: tagged-slot scan. 64 blocks x 512 threads; wave w owns rows
// 16*bid + 2w and 16*bid + 2w + 1.
// ---------------------------------------------------------------------------
__global__ __launch_bounds__(512) void rnn_scan_kernel(
    const float* __restrict__ A_raw, float* out,
    unsigned long long* slots)
{
    const int tid = threadIdx.x;       // 0..511
    const int bid = blockIdx.x;        // 0..63
    const int wave = tid >> 6;         // 0..7
    const int lane = tid & 63;
    const int r0 = (bid << 4) + (wave << 1);   // rows r0, r0+1

    __shared__ float hlds[2][HD];

    // Effective A rows: A_eff[r][k] = 0.1*A_raw[r][k] + 0.9*(k==r)
    float aw0[16], aw1[16];
    #pragma unroll
    for (int j = 0; j < 16; ++j) {
        const int k = lane + (j << 6);
        float v0 = 0.1f * A_raw[(size_t)r0 * HD + k];
        float v1 = 0.1f * A_raw[(size_t)(r0 + 1) * HD + k];
        if (k == r0) v0 += 0.9f;
        if (k == r0 + 1) v1 += 0.9f;
        aw0[j] = v0; aw1[j] = v1;
    }

    // Prefetch Bx for t=0.
    float2 bxn = *(const float2*)&out[r0];

    for (int t = 0; t < T_STEPS; ++t) {
        const float2 bx = bxn;

        // Poll my two adjacent slots of h_{t-1}: ring[(t+3)&3], tag t.
        // vmcnt(0) INSIDE the asm -> writeback synchronous with the stmt;
        // no in-flight VMEM ever crosses compiler-generated code.
        const unsigned long long* sp =
            slots + ((size_t)((t + 3) & 3) << 10) + (tid << 1);
        uint32x4 s;
        do {
            asm volatile(
                "global_load_dwordx4 %0, %1, off sc0 sc1\n\t"
                "s_waitcnt vmcnt(0)"
                : "=v"(s) : "v"(sp));
        } while (s.y != (unsigned)t || s.w != (unsigned)t);

        union { unsigned u; float f; } c0, c1; c0.u = s.x; c1.u = s.z;
        *(float2*)&hlds[t & 1][tid << 1] = make_float2(c0.f, c1.f);
        __syncthreads();

        // Prefetch next step's Bx while h is consumed.
        const int tn = (t + 1 < T_STEPS) ? (t + 1) : t;
        bxn = *(const float2*)&out[(size_t)tn * HD + r0];

        // Both rows' dot products from ONE pass over h in LDS.
        const float* hl = hlds[t & 1];
        float p0 = 0.f, p1 = 0.f;
        #pragma unroll
        for (int j = 0; j < 16; ++j) {
            const float hvj = hl[lane + (j << 6)];
            p0 = fmaf(aw0[j], hvj, p0);
            p1 = fmaf(aw1[j], hvj, p1);
        }

        // Wave-wide sums via DPP (pure VALU, no LDS crossbar).
        // row_shr 1/2/4/8: within-16 inclusive sums (lane 15 of each row =
        // row total). row_bcast:15 rm=0xa: rows 1,3 += their lower row's
        // lane-15 total (lane31 = sum 0..31, lane63 = sum 32..63).
        // row_bcast:31 rm=0xc: rows 2,3 += lane31 (sum 0..31).
        // -> lane 63 holds the full 64-lane sum.
        DPP_ADD(p0, 0x111, 0xf); DPP_ADD(p1, 0x111, 0xf);  // row_shr:1
        DPP_ADD(p0, 0x112, 0xf); DPP_ADD(p1, 0x112, 0xf);  // row_shr:2
        DPP_ADD(p0, 0x114, 0xf); DPP_ADD(p1, 0x114, 0xf);  // row_shr:4
        DPP_ADD(p0, 0x118, 0xf); DPP_ADD(p1, 0x118, 0xf);  // row_shr:8
        DPP_ADD(p0, 0x142, 0xa); DPP_ADD(p1, 0x142, 0xa);  // row_bcast:15
        DPP_ADD(p0, 0x143, 0xc); DPP_ADD(p1, 0x143, 0xc);  // row_bcast:31

        if (lane == 63) {
            const float h0n = fast_tanh(p0 + bx.x);
            const float h1n = fast_tanh(p1 + bx.y);
            union { float f; unsigned u; } u0, u1; u0.f = h0n; u1.f = h1n;
            uint32x4 pkt;
            pkt.x = u0.u; pkt.y = (unsigned)(t + 1);
            pkt.z = u1.u; pkt.w = (unsigned)(t + 1);
            unsigned long long* dp = slots + ((size_t)(t & 3) << 10) + r0;
            // Packet store FIRST (inter-block critical path), out second.
            asm volatile(
                "global_store_dwordx4 %0, %1, off sc0 sc1"
                :: "v"(dp), "v"(pkt) : "memory");
            *(float2*)&out[(size_t)t * HD + r0] = make_float2(h0n, h1n);
        }
        // No grid barrier: tags + 4-deep ring + dataflow (skew <= 1) suffice.
        // LDS double buffer covers intra-block wave skew.
    }
}

// ---------------------------------------------------------------------------
extern "C" void kernel_launch(void* const* d_in, const int* in_sizes, int n_in,
                              void* d_out, int out_size, void* d_ws, size_t ws_size,
                              hipStream_t stream)
{
    const float* x     = (const float*)d_in[0];  // [16384, 512]
    const float* h0    = (const float*)d_in[1];  // [1024]
    const float* A_raw = (const float*)d_in[2];  // [1024, 1024]
    const float* B     = (const float*)d_in[3];  // [1024, 512]
    const float* c     = (const float*)d_in[4];  // [1024]
    float* out = (float*)d_out;                  // [16384, 1024]
    unsigned long long* slots = (unsigned long long*)d_ws;  // 4 x 1024 x 8B

    dim3 gemm_grid(T_STEPS / 64, HD / 64);       // 256 x 16
    gemm_bx_kernel<<<gemm_grid, 256, 0, stream>>>(x, B, c, out);
    init_slots_kernel<<<1, HD, 0, stream>>>(slots, h0);
    rnn_scan_kernel<<<64, 512, 0, stream>>>(A_raw, out, slots);
}